// Round 4
// baseline (337.046 us; speedup 1.0000x reference)
//
#include <hip/hip_runtime.h>
#include <hip/hip_bf16.h>

#define NMAX 64
#define LDA 65   // +1 pad: conflict-free staging writes in the transposed case
#define MAXB 2048

// ---- wave64 f64 cross-lane helpers (DPP + readlane; no ds_bpermute) ----
template <int CTRL>
__device__ __forceinline__ double dpp_min_step(double x) {
    const int lo = __builtin_amdgcn_update_dpp(0, __double2loint(x), CTRL, 0xF, 0xF, true);
    const int hi = __builtin_amdgcn_update_dpp(0, __double2hiint(x), CTRL, 0xF, 0xF, true);
    return fmin(x, __hiloint2double(hi, lo));
}
template <int CTRL>
__device__ __forceinline__ double dpp_add_step(double x) {
    const int lo = __builtin_amdgcn_update_dpp(0, __double2loint(x), CTRL, 0xF, 0xF, true);
    const int hi = __builtin_amdgcn_update_dpp(0, __double2hiint(x), CTRL, 0xF, 0xF, true);
    return x + __hiloint2double(hi, lo);
}
__device__ __forceinline__ double readlane_d(double x, int l) {
    const int lo = __builtin_amdgcn_readlane(__double2loint(x), l);
    const int hi = __builtin_amdgcn_readlane(__double2hiint(x), l);
    return __hiloint2double(hi, lo);
}
__device__ __forceinline__ double wave_sum_f64(double x) {   // exact, each lane once
    x = dpp_add_step<0xB1>(x);  x = dpp_add_step<0x4E>(x);
    x = dpp_add_step<0x141>(x); x = dpp_add_step<0x140>(x);
    x = dpp_add_step<0x142>(x); x = dpp_add_step<0x143>(x);
    return readlane_d(x, 63);
}

// ---- per-problem LAP state (scalarized into registers by SROA) ----
struct Lap {
    double u, v, minv;   // lane r owns u[r+1]; lane j owns v[j+1], minv[j+1]
    int p, way, j0, i0, irow, n, m;
    bool used, rowused, done;
    float aPend;         // prefetched a[i0-1][lane] from LDS
};

// one branchless dijkstra iteration (exact f64 replica of numpy's inner loop)
__device__ __forceinline__ void dij_iter(Lap& s, const float* __restrict__ alds, int lane) {
    if (lane == s.j0 - 1) s.used = true;          // used[j0]=True (j0==0: no lane)
    if (lane == s.i0 - 1) s.rowused = true;       // row i0 joins the tree
    const double ui  = readlane_d(s.u, s.i0 - 1);
    const double aij = -(double)s.aPend;          // minimize -scores
    if (!s.used) {
        const double cur = (aij - ui) - s.v;      // same association as numpy
        if (cur < s.minv) { s.minv = cur; s.way = s.j0; }
    }
    const double contrib = s.used ? 1e18 : s.minv;
    double red = contrib;
    red = dpp_min_step<0xB1>(red);    // xor 1
    red = dpp_min_step<0x4E>(red);    // xor 2
    red = dpp_min_step<0x141>(red);   // xor 4 (row_half_mirror)
    red = dpp_min_step<0x140>(red);   // xor 8 (row_mirror)
    red = dpp_min_step<0x142>(red);   // row_bcast15
    red = dpp_min_step<0x143>(red);   // row_bcast31 -> lane63 = global min
    const double delta = readlane_d(red, 63);
    const unsigned long long em = __ballot(contrib == delta);
    const int j1 = __ffsll(em);                   // tie -> lowest index (np.argmin)
    if (s.rowused) s.u += delta;                  // u[p[j]] += delta (incl. u[i])
    if (s.used) s.v -= delta; else s.minv -= delta;
    s.j0 = j1;
    s.i0 = __builtin_amdgcn_readlane(s.p, j1 - 1);
    const int pr = (s.i0 > 0 ? s.i0 : 1) - 1;     // clamp: harmless read if break
    s.aPend = alds[pr * LDA + lane];              // prefetch next row
}

// augment + next-row reinit when the dijkstra reached a free column (uniform branch)
__device__ __forceinline__ void dij_trans(Lap& s, const float* __restrict__ alds,
                                          int lane, int jj) {
    if (s.i0 != 0) return;
    int j0 = s.j0;
    while (j0) {
        const int j1w  = __builtin_amdgcn_readlane(s.way, j0 - 1);
        const int newp = (j1w == 0) ? s.irow : __builtin_amdgcn_readlane(s.p, j1w - 1);
        if (lane == j0 - 1) s.p = newp;
        j0 = j1w;
    }
    ++s.irow;
    if (s.irow > s.n) { s.done = true; return; }
    s.j0 = 0; s.i0 = s.irow; s.minv = 1e18; s.way = 0;
    s.used = (jj > s.m); s.rowused = false;
    s.aPend = alds[(s.i0 - 1) * LDA + lane];
}

// deterministic similar-size pairing: perm = batches sorted by unique key (n<<11|b)
__global__ __launch_bounds__(256) void rank_kernel(const int* __restrict__ n1s,
                                                   int* __restrict__ perm, int B) {
    __shared__ __align__(16) int keys[MAXB];
    const int t = threadIdx.x;
    const int g = blockIdx.x * 256 + t;
    if (B > MAXB) { if (g < B) perm[g] = g; return; }   // fallback (unused here)
    for (int k = t; k < B; k += 256) keys[k] = (n1s[k] << 11) | k;
    __syncthreads();
    if (g >= B) return;
    const int myk = keys[g];
    int rank = 0;
    const int4* k4 = (const int4*)keys;
    for (int q = 0; q < B / 4; ++q) {                   // broadcast reads, no conflicts
        const int4 kk = k4[q];
        rank += (kk.x < myk) + (kk.y < myk) + (kk.z < myk) + (kk.w < myk);
    }
    for (int k = (B / 4) * 4; k < B; ++k) rank += (keys[k] < myk);
    perm[rank] = g;
}

// one wave solves TWO batches as interleaved state machines (ILP latency hiding)
__global__ __launch_bounds__(64) void hung_pair_kernel(
    const float* __restrict__ pred, const float* __restrict__ gt,
    const int* __restrict__ n1s, const int* __restrict__ n2s,
    const int* __restrict__ perm, double* __restrict__ partial, int B)
{
    const int bid = blockIdx.x;
    const int lane = threadIdx.x & 63;
    const int jj = lane + 1;
    const int bA = perm[2 * bid];
    const bool hasB = (2 * bid + 1) < B;
    const int bB = perm[hasB ? (2 * bid + 1) : (2 * bid)];

    const float* __restrict__ pred0 = pred + (size_t)bA * NMAX * NMAX;
    const float* __restrict__ gt0   = gt   + (size_t)bA * NMAX * NMAX;
    const float* __restrict__ pred1 = pred + (size_t)bB * NMAX * NMAX;
    const float* __restrict__ gt1   = gt   + (size_t)bB * NMAX * NMAX;

    const int n1_0 = n1s[bA], n2_0 = n2s[bA];
    const int n1_1 = n1s[bB], n2_1 = n2s[bB];
    const bool tr0 = (n1_0 > n2_0);
    const bool tr1 = (n1_1 > n2_1);

    __shared__ float alds0[NMAX * LDA];
    __shared__ float alds1[NMAX * LDA];
    {   // stage both cost matrices (lap layout; transpose if n1 > n2)
        const float4* p40 = (const float4*)pred0;
        const float4* p41 = (const float4*)pred1;
        #pragma unroll
        for (int it = 0; it < 16; ++it) {
            const float4 v0 = p40[it * 64 + lane];
            const float4 v1 = p41[it * 64 + lane];
            const int r = it * 4 + (lane >> 4);
            const int c = (lane & 15) * 4;
            if (!tr0) {
                alds0[r * LDA + c + 0] = v0.x; alds0[r * LDA + c + 1] = v0.y;
                alds0[r * LDA + c + 2] = v0.z; alds0[r * LDA + c + 3] = v0.w;
            } else {
                alds0[(c + 0) * LDA + r] = v0.x; alds0[(c + 1) * LDA + r] = v0.y;
                alds0[(c + 2) * LDA + r] = v0.z; alds0[(c + 3) * LDA + r] = v0.w;
            }
            if (!tr1) {
                alds1[r * LDA + c + 0] = v1.x; alds1[r * LDA + c + 1] = v1.y;
                alds1[r * LDA + c + 2] = v1.z; alds1[r * LDA + c + 3] = v1.w;
            } else {
                alds1[(c + 0) * LDA + r] = v1.x; alds1[(c + 1) * LDA + r] = v1.y;
                alds1[(c + 2) * LDA + r] = v1.z; alds1[(c + 3) * LDA + r] = v1.w;
            }
        }
    }
    __syncthreads();

    Lap s0, s1;
    s0.u = 0.0; s0.v = 0.0; s0.minv = 1e18; s0.p = 0; s0.way = 0;
    s0.n = tr0 ? n2_0 : n1_0; s0.m = tr0 ? n1_0 : n2_0;
    s0.irow = 1; s0.j0 = 0; s0.i0 = 1; s0.used = (jj > s0.m); s0.rowused = false;
    s0.done = false; s0.aPend = alds0[lane];
    s1.u = 0.0; s1.v = 0.0; s1.minv = 1e18; s1.p = 0; s1.way = 0;
    s1.n = tr1 ? n2_1 : n1_1; s1.m = tr1 ? n1_1 : n2_1;
    s1.irow = 1; s1.j0 = 0; s1.i0 = 1; s1.used = (jj > s1.m); s1.rowused = false;
    s1.done = !hasB; s1.aPend = alds1[lane];

    // fused loop: straight-line A-step + B-step (scheduler interleaves the two
    // independent chains; each prefetched ds_read is covered by the other body),
    // then rare uniform transition branches.
    while (!s0.done && !s1.done) {
        dij_iter(s0, alds0, lane);
        dij_iter(s1, alds1, lane);
        dij_trans(s0, alds0, lane, jj);
        dij_trans(s1, alds1, lane, jj);
    }
    while (!s0.done) { dij_iter(s0, alds0, lane); dij_trans(s0, alds0, lane, jj); }
    while (!s1.done) { dij_iter(s1, alds1, lane); dij_trans(s1, alds1, lane, jj); }

    // ---- fused loss epilogue (f32 BCE exactly as reference) ----
    double ls0 = 0.0, ls1 = 0.0;
    for (int i2 = 0; i2 < NMAX; ++i2) {
        const float pv0 = pred0[i2 * NMAX + lane];
        const float gv0 = gt0[i2 * NMAX + lane];
        const float pv1 = pred1[i2 * NMAX + lane];
        const float gv1 = gt1[i2 * NMAX + lane];
        float dis0, dis1;
        if (!tr0) dis0 = (s0.p == i2 + 1) ? 1.0f : 0.0f;
        else      dis0 = (__builtin_amdgcn_readlane(s0.p, i2) - 1 == lane) ? 1.0f : 0.0f;
        if (!tr1) dis1 = (s1.p == i2 + 1) ? 1.0f : 0.0f;
        else      dis1 = (__builtin_amdgcn_readlane(s1.p, i2) - 1 == lane) ? 1.0f : 0.0f;
        float ali0 = dis0 + gv0; if (ali0 > 1.0f) ali0 = 0.9f;
        float ali1 = dis1 + gv1; if (ali1 > 1.0f) ali1 = 0.9f;
        const float pp0 = ali0 * pv0, gg0 = ali0 * gv0;
        const float pp1 = ali1 * pv1, gg1 = ali1 * gv1;
        const float b0 = -(gg0 * fmaxf(logf(pp0), -100.0f)
                           + (1.0f - gg0) * fmaxf(log1pf(-pp0), -100.0f));
        const float b1 = -(gg1 * fmaxf(logf(pp1), -100.0f)
                           + (1.0f - gg1) * fmaxf(log1pf(-pp1), -100.0f));
        if (i2 < n1_0 && lane < n2_0) ls0 += (double)b0;
        if (i2 < n1_1 && lane < n2_1) ls1 += (double)b1;
    }
    const double t0 = wave_sum_f64(ls0);
    const double t1 = wave_sum_f64(ls1);
    if (lane == 0) {
        partial[bA] = t0;
        if (hasB) partial[bB] = t1;
    }
}

__global__ __launch_bounds__(256) void finalize_kernel(
    const double* __restrict__ partial, const int* __restrict__ n1s,
    float* __restrict__ out, int B)
{
    __shared__ double sred[256];
    __shared__ int    nred[256];
    const int t = threadIdx.x;
    double s = 0.0;
    int ns = 0;
    for (int bb = t; bb < B; bb += 256) { s += partial[bb]; ns += n1s[bb]; }
    sred[t] = s; nred[t] = ns;
    __syncthreads();
    for (int off = 128; off >= 1; off >>= 1) {
        if (t < off) { sred[t] += sred[t + off]; nred[t] += nred[t + off]; }
        __syncthreads();
    }
    if (t == 0) out[0] = (float)sred[0] / (float)nred[0];
}

extern "C" void kernel_launch(void* const* d_in, const int* in_sizes, int n_in,
                              void* d_out, int out_size, void* d_ws, size_t ws_size,
                              hipStream_t stream) {
    const float* pred = (const float*)d_in[0];   // [B,64,64] f32
    const float* gt   = (const float*)d_in[1];   // [B,64,64] f32
    const int* n1s    = (const int*)d_in[2];     // [B] i32
    const int* n2s    = (const int*)d_in[3];     // [B] i32
    float* out = (float*)d_out;                  // scalar f32
    const int B = in_sizes[2];
    double* partial = (double*)d_ws;                         // B doubles
    int* perm = (int*)((char*)d_ws + (size_t)B * sizeof(double)); // B ints

    rank_kernel<<<(B + 255) / 256, 256, 0, stream>>>(n1s, perm, B);
    hung_pair_kernel<<<(B + 1) / 2, 64, 0, stream>>>(pred, gt, n1s, n2s, perm, partial, B);
    finalize_kernel<<<1, 256, 0, stream>>>(partial, n1s, out, B);
}

// Round 5
// 205.202 us; speedup vs baseline: 1.6425x; 1.6425x over previous
//
#include <hip/hip_runtime.h>
#include <hip/hip_bf16.h>

#define NMAX 64
#define LDA 65   // +1 pad: conflict-free staging writes in the transposed case

// ---- cross-lane helpers: readlane (uniform idx), DPP reduce, sgpr-mask select ----
__device__ __forceinline__ double readlane_d(double x, int l) {
    const int lo = __builtin_amdgcn_readlane(__double2loint(x), l);
    const int hi = __builtin_amdgcn_readlane(__double2hiint(x), l);
    return __hiloint2double(hi, lo);
}
template <int CTRL>
__device__ __forceinline__ unsigned dpp_umin(unsigned x) {
    const unsigned t = (unsigned)__builtin_amdgcn_update_dpp(0, (int)x, CTRL, 0xF, 0xF, true);
    return x < t ? x : t;          // folds to v_min_u32_dpp
}
template <int CTRL>
__device__ __forceinline__ double dpp_add_step(double x) {
    const int lo = __builtin_amdgcn_update_dpp(0, __double2loint(x), CTRL, 0xF, 0xF, true);
    const int hi = __builtin_amdgcn_update_dpp(0, __double2hiint(x), CTRL, 0xF, 0xF, true);
    return x + __hiloint2double(hi, lo);
}
__device__ __forceinline__ double wave_sum_f64(double x) {   // exact, each lane once
    x = dpp_add_step<0xB1>(x);  x = dpp_add_step<0x4E>(x);
    x = dpp_add_step<0x141>(x); x = dpp_add_step<0x140>(x);
    x = dpp_add_step<0x142>(x); x = dpp_add_step<0x143>(x);
    return readlane_d(x, 63);
}
// mask-lane ? a : b  (mask is a wave-uniform 64-bit value in SGPRs)
__device__ __forceinline__ unsigned sel_u32(unsigned long long m, unsigned a, unsigned b) {
    unsigned r;
    asm("v_cndmask_b32 %0, %1, %2, %3" : "=v"(r) : "v"(b), "v"(a), "s"(m));
    return r;
}
__device__ __forceinline__ int sel_i32(unsigned long long m, int a, int b) {
    int r;
    asm("v_cndmask_b32 %0, %1, %2, %3" : "=v"(r) : "v"(b), "v"(a), "s"(m));
    return r;
}
__device__ __forceinline__ double sel_f64(unsigned long long m, double a, double b) {
    const unsigned lo = sel_u32(m, (unsigned)__double2loint(a), (unsigned)__double2loint(b));
    const unsigned hi = sel_u32(m, (unsigned)__double2hiint(a), (unsigned)__double2hiint(b));
    return __hiloint2double((int)hi, (int)lo);
}

// One wave (64 lanes) per batch: Jonker-Volgenant LAP, exact float64 replica of
// the numpy reference, + fused masked-BCE loss epilogue.
// lane j owns column j+1 (v, minv, way, p); lane r owns row-dual u[r+1].
// used/rowused tracked as uniform SGPR bitmasks (SALU); argmin via two-stage
// u32 DPP min on order-preserving keys (exact IEEE order, first-occurrence tie).
__global__ __launch_bounds__(64) void hung_loss_kernel(
    const float* __restrict__ pred, const float* __restrict__ gt,
    const int* __restrict__ n1s, const int* __restrict__ n2s,
    double* __restrict__ partial)
{
    const int b = blockIdx.x;
    const int lane = threadIdx.x & 63;
    const float* __restrict__ predb = pred + (size_t)b * NMAX * NMAX;
    const float* __restrict__ gtb   = gt   + (size_t)b * NMAX * NMAX;
    const int n1 = n1s[b];
    const int n2 = n2s[b];
    const bool trans = (n1 > n2);                  // lap requires n <= m
    const int n = trans ? n2 : n1;
    const int m = trans ? n1 : n2;

    // ---- stage cost matrix into LDS (lap layout: a_lds[r*LDA+c] = scores[LAP r][LAP c]) ----
    __shared__ float a_lds[NMAX * LDA];
    {
        const float4* p4 = (const float4*)predb;
        #pragma unroll
        for (int it = 0; it < 16; ++it) {
            const float4 val = p4[it * 64 + lane];
            const int r = it * 4 + (lane >> 4);    // source row in pred
            const int c = (lane & 15) * 4;         // source col in pred
            if (!trans) {
                a_lds[r * LDA + c + 0] = val.x; a_lds[r * LDA + c + 1] = val.y;
                a_lds[r * LDA + c + 2] = val.z; a_lds[r * LDA + c + 3] = val.w;
            } else {
                a_lds[(c + 0) * LDA + r] = val.x; a_lds[(c + 1) * LDA + r] = val.y;
                a_lds[(c + 2) * LDA + r] = val.z; a_lds[(c + 3) * LDA + r] = val.w;
            }
        }
    }
    __syncthreads();

    double u_reg = 0.0;  // lane r owns u[r+1] (row dual)
    double v = 0.0;      // lane j owns v[j+1] (column dual)
    int p = 0;           // row matched to this column (1-based), 0 = free
    const unsigned long long fake = (m < 64) ? (~0ull << m) : 0ull;  // cols > m

    for (int i = 1; i <= n; ++i) {
        int j0 = 0;
        int i0 = i;                                // i0 = p[j0]; p[0] = i
        double minv = 1e18;
        int way = 0;
        unsigned long long used_mask = fake;       // SALU-maintained
        unsigned long long row_mask = 0ull;        // rows on the tree
        while (true) {
            row_mask |= 1ull << (i0 - 1);          // row i0 joins the tree
            const double ui  = readlane_d(u_reg, i0 - 1);
            const double aij = -(double)a_lds[(i0 - 1) * LDA + lane]; // minimize -scores
            const double cur = (aij - ui) - v;     // same association as numpy
            // upd = free & (cur < minv)
            const unsigned long long upd = __ballot(cur < minv) & ~used_mask;
            minv = sel_f64(upd, cur, minv);
            way  = sel_i32(upd, j0, way);
            // order-preserving u32 key of minv's hi word; used lanes forced to max
            const int h = __double2hiint(minv);
            unsigned khi = (unsigned)h ^ (unsigned)((h >> 31) | 0x80000000);
            khi = sel_u32(used_mask, 0xFFFFFFFFu, khi);
            unsigned red = khi;
            red = dpp_umin<0xB1>(red);     // xor 1
            red = dpp_umin<0x4E>(red);     // xor 2
            red = dpp_umin<0x141>(red);    // row_half_mirror
            red = dpp_umin<0x140>(red);    // row_mirror
            red = dpp_umin<0x142>(red);    // row_bcast15
            red = dpp_umin<0x143>(red);    // row_bcast31 -> lane63 = global min
            const unsigned H = (unsigned)__builtin_amdgcn_readlane((int)red, 63);
            const unsigned long long tie = __ballot(khi == H);
            int j1;
            if ((tie & (tie - 1)) == 0ull) {
                j1 = __ffsll(tie);                 // unique hi-key min
            } else {                               // rare: resolve full IEEE order on lo32
                const unsigned klo = (unsigned)__double2loint(minv) ^ (unsigned)(h >> 31);
                unsigned klo2 = sel_u32(tie, klo, 0xFFFFFFFFu);
                unsigned red2 = klo2;
                red2 = dpp_umin<0xB1>(red2);  red2 = dpp_umin<0x4E>(red2);
                red2 = dpp_umin<0x141>(red2); red2 = dpp_umin<0x140>(red2);
                red2 = dpp_umin<0x142>(red2); red2 = dpp_umin<0x143>(red2);
                const unsigned L = (unsigned)__builtin_amdgcn_readlane((int)red2, 63);
                const unsigned long long tie2 = __ballot(klo2 == L) & tie;
                j1 = __ffsll(tie2);                // first occurrence = np.argmin
            }
            const double delta = readlane_d(minv, j1 - 1);   // exact f64 min
            // dual updates (exact per-iteration association)
            const double tu = u_reg + delta;
            u_reg = sel_f64(row_mask, tu, u_reg);  // u[p[j] on tree] += delta (incl. u[i])
            const double tv = v - delta;
            v = sel_f64(used_mask, tv, v);         // v[used] -= delta
            minv = minv - delta;                   // free semantics; used lanes drift (masked)
            used_mask |= 1ull << (j1 - 1);         // used[j1] for next iteration
            j0 = j1;
            i0 = __builtin_amdgcn_readlane(p, j1 - 1);       // p[j1]; 0 => free column
            if (i0 == 0) break;
        }
        // augment along way[] back to column 0
        while (j0 > 0) {
            const int j1w = __builtin_amdgcn_readlane(way, j0 - 1);
            const int newp = (j1w == 0) ? i : __builtin_amdgcn_readlane(p, j1w - 1);
            if (lane == j0 - 1) p = newp;
            j0 = j1w;
        }
    }

    // ---- fused loss: dis[i][j] from lane-held p; BCE in f32 like reference ----
    double lsum = 0.0;
    for (int i2 = 0; i2 < NMAX; ++i2) {
        const float pv = predb[i2 * NMAX + lane];
        const float gv = gtb[i2 * NMAX + lane];
        float dis;
        if (!trans) {
            dis = (p == i2 + 1) ? 1.0f : 0.0f;             // col lane matched to row p-1
        } else {
            const int pi = __builtin_amdgcn_readlane(p, i2);  // lap-col i2+1 == scores-row i2
            dis = (pi - 1 == lane) ? 1.0f : 0.0f;
        }
        float ali = dis + gv;
        if (ali > 1.0f) ali = 0.9f;
        const float pp = ali * pv;
        const float gg = ali * gv;
        const float lp  = fmaxf(logf(pp),    -100.0f);     // clip(log(p), -100)
        const float l1p = fmaxf(log1pf(-pp), -100.0f);     // clip(log1p(-p), -100)
        const float bce = -(gg * lp + (1.0f - gg) * l1p);
        if (i2 < n1 && lane < n2) lsum += (double)bce;
    }
    const double tsum = wave_sum_f64(lsum);
    if (lane == 0) partial[b] = tsum;
}

__global__ __launch_bounds__(256) void finalize_kernel(
    const double* __restrict__ partial, const int* __restrict__ n1s,
    float* __restrict__ out, int B)
{
    __shared__ double sred[256];
    __shared__ int    nred[256];
    const int t = threadIdx.x;
    double s = 0.0;
    int ns = 0;
    for (int bb = t; bb < B; bb += 256) { s += partial[bb]; ns += n1s[bb]; }
    sred[t] = s; nred[t] = ns;
    __syncthreads();
    for (int off = 128; off >= 1; off >>= 1) {
        if (t < off) { sred[t] += sred[t + off]; nred[t] += nred[t + off]; }
        __syncthreads();
    }
    if (t == 0) out[0] = (float)sred[0] / (float)nred[0];
}

extern "C" void kernel_launch(void* const* d_in, const int* in_sizes, int n_in,
                              void* d_out, int out_size, void* d_ws, size_t ws_size,
                              hipStream_t stream) {
    const float* pred = (const float*)d_in[0];   // [B,64,64] f32
    const float* gt   = (const float*)d_in[1];   // [B,64,64] f32
    const int* n1s    = (const int*)d_in[2];     // [B] i32
    const int* n2s    = (const int*)d_in[3];     // [B] i32
    float* out = (float*)d_out;                  // scalar f32
    double* partial = (double*)d_ws;             // B doubles (16 KB)
    const int B = in_sizes[2];

    hung_loss_kernel<<<B, 64, 0, stream>>>(pred, gt, n1s, n2s, partial);
    finalize_kernel<<<1, 256, 0, stream>>>(partial, n1s, out, B);
}

// Round 6
// 190.726 us; speedup vs baseline: 1.7672x; 1.0759x over previous
//
#include <hip/hip_runtime.h>
#include <hip/hip_bf16.h>

#define NMAX 64

typedef float f32x32 __attribute__((ext_vector_type(32)));

// ---- cross-lane helpers: readlane (uniform idx), DPP reduce, sgpr-mask select ----
__device__ __forceinline__ double readlane_d(double x, int l) {
    const int lo = __builtin_amdgcn_readlane(__double2loint(x), l);
    const int hi = __builtin_amdgcn_readlane(__double2hiint(x), l);
    return __hiloint2double(hi, lo);
}
template <int CTRL>
__device__ __forceinline__ unsigned dpp_umin(unsigned x) {
    const unsigned t = (unsigned)__builtin_amdgcn_update_dpp(0, (int)x, CTRL, 0xF, 0xF, true);
    return x < t ? x : t;          // folds to v_min_u32_dpp
}
template <int CTRL>
__device__ __forceinline__ double dpp_add_step(double x) {
    const int lo = __builtin_amdgcn_update_dpp(0, __double2loint(x), CTRL, 0xF, 0xF, true);
    const int hi = __builtin_amdgcn_update_dpp(0, __double2hiint(x), CTRL, 0xF, 0xF, true);
    return x + __hiloint2double(hi, lo);
}
__device__ __forceinline__ double wave_sum_f64(double x) {   // exact, each lane once
    x = dpp_add_step<0xB1>(x);  x = dpp_add_step<0x4E>(x);
    x = dpp_add_step<0x141>(x); x = dpp_add_step<0x140>(x);
    x = dpp_add_step<0x142>(x); x = dpp_add_step<0x143>(x);
    return readlane_d(x, 63);
}
// mask-lane ? a : b  (mask is a wave-uniform 64-bit value in SGPRs)
__device__ __forceinline__ unsigned sel_u32(unsigned long long m, unsigned a, unsigned b) {
    unsigned r;
    asm("v_cndmask_b32 %0, %1, %2, %3" : "=v"(r) : "v"(b), "v"(a), "s"(m));
    return r;
}
__device__ __forceinline__ int sel_i32(unsigned long long m, int a, int b) {
    int r;
    asm("v_cndmask_b32 %0, %1, %2, %3" : "=v"(r) : "v"(b), "v"(a), "s"(m));
    return r;
}
__device__ __forceinline__ double sel_f64(unsigned long long m, double a, double b) {
    const unsigned lo = sel_u32(m, (unsigned)__double2loint(a), (unsigned)__double2loint(b));
    const unsigned hi = sel_u32(m, (unsigned)__double2hiint(a), (unsigned)__double2hiint(b));
    return __hiloint2double((int)hi, (int)lo);
}

// One wave (64 lanes) per batch: Jonker-Volgenant LAP, exact float64 replica of
// the numpy reference, + fused masked-BCE loss epilogue.
// lane j owns column j+1 of the LAP matrix IN REGISTERS (2x f32x32, indexed via
// uniform dynamic extract -> v_movrels), plus v[j+1], minv[j+1], way, p;
// lane r owns row-dual u[r+1]. used/rowused are uniform SGPR bitmasks (SALU).
// Argmin via u32 DPP min on order-preserving keys (exact IEEE order,
// first-occurrence tie-break == np.argmin).
__global__ __launch_bounds__(64, 2) void hung_loss_kernel(
    const float* __restrict__ pred, const float* __restrict__ gt,
    const int* __restrict__ n1s, const int* __restrict__ n2s,
    double* __restrict__ partial)
{
    const int b = blockIdx.x;
    const int lane = threadIdx.x & 63;
    const float* __restrict__ predb = pred + (size_t)b * NMAX * NMAX;
    const float* __restrict__ gtb   = gt   + (size_t)b * NMAX * NMAX;
    const int n1 = n1s[b];
    const int n2 = n2s[b];
    const bool trans = (n1 > n2);                  // lap requires n <= m
    const int n = trans ? n2 : n1;
    const int m = trans ? n1 : n2;

    // ---- load LAP matrix into registers: lane j holds lap[:, j] (64 f32) ----
    f32x32 alo, ahi;
    if (!trans) {                                  // lap == scores
        #pragma unroll
        for (int r = 0; r < 32; ++r) alo[r] = predb[r * NMAX + lane];
        #pragma unroll
        for (int r = 0; r < 32; ++r) ahi[r] = predb[(r + 32) * NMAX + lane];
    } else {                                       // lap = scores^T: lap[r][j]=pred[j][r]
        #pragma unroll
        for (int r = 0; r < 32; ++r) alo[r] = predb[lane * NMAX + r];
        #pragma unroll
        for (int r = 0; r < 32; ++r) ahi[r] = predb[lane * NMAX + 32 + r];
    }

    double u_reg = 0.0;  // lane r owns u[r+1] (row dual)
    double v = 0.0;      // lane j owns v[j+1] (column dual)
    int p = 0;           // row matched to this column (1-based), 0 = free
    const unsigned long long fake = (m < 64) ? (~0ull << m) : 0ull;  // cols > m
    const unsigned KMAX = 0xFFFFFFFFu;

    for (int i = 1; i <= n; ++i) {
        int j0 = 0;
        int i0 = i;                                // i0 = p[j0]; p[0] = i
        double minv = 1e18;
        int way = 0;
        unsigned long long used_mask = fake;       // SALU-maintained
        unsigned long long row_mask = 0ull;        // rows on the tree
        const int hinit = __double2hiint(minv);
        unsigned khi = (unsigned)hinit ^ (unsigned)((hinit >> 31) | 0x80000000);
        // prefetch first row (uniform dynamic extract -> v_movrels)
        int rr = i0 - 1;
        float aval;
        { const float aL = alo[rr & 31], aH = ahi[rr & 31]; aval = (rr & 32) ? aH : aL; }
        while (true) {
            row_mask |= 1ull << (i0 - 1);          // row i0 joins the tree
            const double ui  = readlane_d(u_reg, i0 - 1);
            const double aij = -(double)aval;      // minimize -scores
            const double cur = (aij - ui) - v;     // same association as numpy
            const int hc = __double2hiint(cur);
            const unsigned kcur = (unsigned)hc ^ (unsigned)((hc >> 31) | 0x80000000);
            // upd = free & (cur < minv)
            const unsigned long long upd = __ballot(cur < minv) & ~used_mask;
            minv = sel_f64(upd, cur, minv);
            khi  = sel_u32(upd, kcur, khi);
            way  = sel_i32(upd, j0, way);
            const unsigned kmask = sel_u32(used_mask, KMAX, khi);  // used -> max
            unsigned red = kmask;
            red = dpp_umin<0xB1>(red);     // xor 1
            red = dpp_umin<0x4E>(red);     // xor 2
            red = dpp_umin<0x141>(red);    // row_half_mirror
            red = dpp_umin<0x140>(red);    // row_mirror
            red = dpp_umin<0x142>(red);    // row_bcast15
            red = dpp_umin<0x143>(red);    // row_bcast31 -> lane63 = global min
            const unsigned H = (unsigned)__builtin_amdgcn_readlane((int)red, 63);
            const unsigned long long tie = __ballot(kmask == H);
            int j1;
            if ((tie & (tie - 1)) == 0ull) {
                j1 = __ffsll(tie);                 // unique hi-key min
            } else {                               // rare: resolve full IEEE order on lo32
                const int hm = __double2hiint(minv);
                unsigned klo = (unsigned)__double2loint(minv) ^ (unsigned)(hm >> 31);
                klo = sel_u32(tie, klo, KMAX);
                unsigned red2 = klo;
                red2 = dpp_umin<0xB1>(red2);  red2 = dpp_umin<0x4E>(red2);
                red2 = dpp_umin<0x141>(red2); red2 = dpp_umin<0x140>(red2);
                red2 = dpp_umin<0x142>(red2); red2 = dpp_umin<0x143>(red2);
                const unsigned L = (unsigned)__builtin_amdgcn_readlane((int)red2, 63);
                const unsigned long long tie2 = __ballot(klo == L) & tie;
                j1 = __ffsll(tie2);                // first occurrence = np.argmin
            }
            const double delta = readlane_d(minv, j1 - 1);   // exact f64 min
            // launch next-row access early (off the delta path)
            j0 = j1;
            i0 = __builtin_amdgcn_readlane(p, j1 - 1);       // p[j1]; 0 => free column
            rr = (i0 > 0 ? i0 : 1) - 1;                      // clamped (unused on break)
            { const float aL = alo[rr & 31], aH = ahi[rr & 31]; aval = (rr & 32) ? aH : aL; }
            // dual updates (exact per-iteration association)
            u_reg = sel_f64(row_mask, u_reg + delta, u_reg); // u[tree rows] += delta
            v     = sel_f64(used_mask, v - delta, v);        // v[used] -= delta
            minv  = minv - delta;                 // free semantics; used lanes drift (masked)
            const int h2 = __double2hiint(minv);
            khi = (unsigned)h2 ^ (unsigned)((h2 >> 31) | 0x80000000);
            used_mask |= 1ull << (j1 - 1);        // used[j1] for next iteration
            if (i0 == 0) break;
        }
        // augment along way[] back to column 0
        while (j0 > 0) {
            const int j1w = __builtin_amdgcn_readlane(way, j0 - 1);
            const int newp = (j1w == 0) ? i : __builtin_amdgcn_readlane(p, j1w - 1);
            if (lane == j0 - 1) p = newp;
            j0 = j1w;
        }
    }

    // ---- fused loss: dis[i][j] from lane-held p; BCE in f32 like reference ----
    double lsum = 0.0;
    if (!trans) {
        #pragma unroll
        for (int i2 = 0; i2 < NMAX; ++i2) {
            const float pv = (i2 < 32) ? alo[i2] : ahi[i2 - 32];   // static extract
            const float gv = gtb[i2 * NMAX + lane];
            const float dis = (p == i2 + 1) ? 1.0f : 0.0f;         // col lane <- row p-1
            float ali = dis + gv;
            if (ali > 1.0f) ali = 0.9f;
            const float pp = ali * pv;
            const float gg = ali * gv;
            const float lp  = fmaxf(logf(pp),    -100.0f);         // clip(log(p), -100)
            const float l1p = fmaxf(log1pf(-pp), -100.0f);         // clip(log1p(-p), -100)
            const float bce = -(gg * lp + (1.0f - gg) * l1p);
            if (i2 < n1 && lane < n2) lsum += (double)bce;
        }
    } else {
        for (int i2 = 0; i2 < NMAX; ++i2) {
            const float pv = predb[i2 * NMAX + lane];
            const float gv = gtb[i2 * NMAX + lane];
            const int pi = __builtin_amdgcn_readlane(p, i2);  // lap-col i2+1 == scores-row i2
            const float dis = (pi - 1 == lane) ? 1.0f : 0.0f;
            float ali = dis + gv;
            if (ali > 1.0f) ali = 0.9f;
            const float pp = ali * pv;
            const float gg = ali * gv;
            const float lp  = fmaxf(logf(pp),    -100.0f);
            const float l1p = fmaxf(log1pf(-pp), -100.0f);
            const float bce = -(gg * lp + (1.0f - gg) * l1p);
            if (i2 < n1 && lane < n2) lsum += (double)bce;
        }
    }
    const double tsum = wave_sum_f64(lsum);
    if (lane == 0) partial[b] = tsum;
}

__global__ __launch_bounds__(256) void finalize_kernel(
    const double* __restrict__ partial, const int* __restrict__ n1s,
    float* __restrict__ out, int B)
{
    __shared__ double sred[256];
    __shared__ int    nred[256];
    const int t = threadIdx.x;
    double s = 0.0;
    int ns = 0;
    for (int bb = t; bb < B; bb += 256) { s += partial[bb]; ns += n1s[bb]; }
    sred[t] = s; nred[t] = ns;
    __syncthreads();
    for (int off = 128; off >= 1; off >>= 1) {
        if (t < off) { sred[t] += sred[t + off]; nred[t] += nred[t + off]; }
        __syncthreads();
    }
    if (t == 0) out[0] = (float)sred[0] / (float)nred[0];
}

extern "C" void kernel_launch(void* const* d_in, const int* in_sizes, int n_in,
                              void* d_out, int out_size, void* d_ws, size_t ws_size,
                              hipStream_t stream) {
    const float* pred = (const float*)d_in[0];   // [B,64,64] f32
    const float* gt   = (const float*)d_in[1];   // [B,64,64] f32
    const int* n1s    = (const int*)d_in[2];     // [B] i32
    const int* n2s    = (const int*)d_in[3];     // [B] i32
    float* out = (float*)d_out;                  // scalar f32
    double* partial = (double*)d_ws;             // B doubles (16 KB)
    const int B = in_sizes[2];

    hung_loss_kernel<<<B, 64, 0, stream>>>(pred, gt, n1s, n2s, partial);
    finalize_kernel<<<1, 256, 0, stream>>>(partial, n1s, out, B);
}